// Round 1
// baseline (215.545 us; speedup 1.0000x reference)
//
#include <hip/hip_runtime.h>
#include <hip/hip_bf16.h>
#include <math.h>

typedef unsigned short ushort_t;
typedef __attribute__((ext_vector_type(8))) short bf16x8;
typedef __attribute__((ext_vector_type(4))) float f32x4;
typedef __attribute__((ext_vector_type(2))) float f32x2;

constexpr int BATCH   = 4;
constexpr int D_MODEL = 256;
constexpr int LEN_IN  = 5440;
constexpr int LEN_Q   = 5440;
constexpr int M_TOT   = BATCH * LEN_Q;   // 21760

#define ASG __attribute__((address_space(1)))
#define ASL __attribute__((address_space(3)))

__device__ __forceinline__ void gld16(const void* g, void* l) {
    __builtin_amdgcn_global_load_lds((ASG const void*)g, (ASL void*)l, 16, 0, 0);
}

__device__ __forceinline__ ushort_t bfbits(float x) {
    __hip_bfloat16 h = __float2bfloat16(x);
    ushort_t u; __builtin_memcpy(&u, &h, 2); return u;
}
__device__ __forceinline__ unsigned pk2(float a, float b) {
    return (unsigned)bfbits(a) | ((unsigned)bfbits(b) << 16);
}

// ======================= pack / convert / transpose =======================
__global__ __launch_bounds__(256) void pack_inputs(
    const float* __restrict__ inflat, const float* __restrict__ query,
    const float* __restrict__ Wv, const float* __restrict__ Wo,
    const float* __restrict__ Wa, const float* __restrict__ Wout,
    const float* __restrict__ b_off, const float* __restrict__ b_attn,
    ushort_t* __restrict__ in_bf, ushort_t* __restrict__ q_bf,
    ushort_t* __restrict__ wvT, ushort_t* __restrict__ woaT,
    ushort_t* __restrict__ woutT, float* __restrict__ bias_oa)
{
    const int blk = blockIdx.x, tid = threadIdx.x;
    if (blk < 5440) {
        const float* src = (blk < 2720) ? inflat : query;
        ushort_t*    dst = (blk < 2720) ? in_bf : q_bf;
        const int rb = (blk < 2720) ? blk : blk - 2720;
        const size_t base = (size_t)rb * 2048 + tid * 8;
        float4 a = *(const float4*)(src + base);
        float4 b = *(const float4*)(src + base + 4);
        uint4 o;
        o.x = pk2(a.x, a.y); o.y = pk2(a.z, a.w);
        o.z = pk2(b.x, b.y); o.w = pk2(b.z, b.w);
        *(uint4*)(dst + base) = o;
    } else if (blk < 5504) {
        const float* src = (blk < 5472) ? Wv : Wout;
        ushort_t*    dst = (blk < 5472) ? wvT : woutT;
        const int base = (blk - ((blk < 5472) ? 5440 : 5472)) * 2048;
#pragma unroll
        for (int i = 0; i < 8; i++) {
            const int idx = base + i * 256 + tid;
            const int k = idx >> 8, n = idx & 255;
            dst[n * 256 + k] = bfbits(src[idx]);
        }
    } else if (blk < 5552) {
        const int base = (blk - 5504) * 2048;
#pragma unroll
        for (int i = 0; i < 8; i++) {
            const int idx = base + i * 256 + tid;   // < 98304
            const int k = idx / 384, j = idx - k * 384;
            const float v = (j < 256) ? Wo[k * 256 + j] : Wa[k * 128 + (j - 256)];
            woaT[j * 256 + k] = bfbits(v);
        }
    } else {
        bias_oa[tid] = b_off[tid];
        if (tid < 128) bias_oa[256 + tid] = b_attn[tid];
    }
}

// ======================= bf16 MFMA GEMM core =======================
// OUT_MODE: 0 = f32 row-major, 1 = bf16 row-major, 2 = bf16 head-major value
template <int OUT_MODE>
__device__ __forceinline__ void gemm_core(
    const ushort_t* __restrict__ A, const ushort_t* __restrict__ BT,
    const float* __restrict__ bias, void* __restrict__ Cp, int N,
    int bm, int bn, ushort_t* As, ushort_t* Bs)
{
    const int tid  = threadIdx.x;
    const int wave = tid >> 6, lane = tid & 63;
    const int wm = (wave >> 1) * 64, wn = (wave & 1) * 64;
    const int c0 = 2 * wave, c1 = 2 * wave + 1;
    const int kb = (lane & 3) * 8;
    const ushort_t* gA0 = A  + (size_t)(bm + c0 * 16 + (lane >> 2)) * 256 + kb;
    const ushort_t* gA1 = A  + (size_t)(bm + c1 * 16 + (lane >> 2)) * 256 + kb;
    const ushort_t* gB0 = BT + (size_t)(bn + c0 * 16 + (lane >> 2)) * 256 + kb;
    const ushort_t* gB1 = BT + (size_t)(bn + c1 * 16 + (lane >> 2)) * 256 + kb;
    ushort_t* lA0 = As + c0 * 512;
    ushort_t* lA1 = As + c1 * 512;
    ushort_t* lB0 = Bs + c0 * 512;
    ushort_t* lB1 = Bs + c1 * 512;

    f32x4 acc[4][4] = {};

    const int row = lane & 15, kg = (lane >> 4) * 8;
    for (int kt = 0; kt < 8; kt++) {
        gld16(gA0, lA0); gld16(gA1, lA1);
        gld16(gB0, lB0); gld16(gB1, lB1);
        gA0 += 32; gA1 += 32; gB0 += 32; gB1 += 32;
        __syncthreads();
        bf16x8 af[4], bfr[4];
#pragma unroll
        for (int i = 0; i < 4; i++)
            af[i] = *(const bf16x8*)(As + (wm + i * 16 + row) * 32 + kg);
#pragma unroll
        for (int j = 0; j < 4; j++)
            bfr[j] = *(const bf16x8*)(Bs + (wn + j * 16 + row) * 32 + kg);
#pragma unroll
        for (int i = 0; i < 4; i++)
#pragma unroll
            for (int j = 0; j < 4; j++)
                acc[i][j] = __builtin_amdgcn_mfma_f32_16x16x32_bf16(
                    af[i], bfr[j], acc[i][j], 0, 0, 0);
        __syncthreads();
    }

    const int col = lane & 15, rbase = (lane >> 4) * 4;
#pragma unroll
    for (int j = 0; j < 4; j++) {
        const int cc = bn + wn + j * 16 + col;
        const float bv = bias[cc];
#pragma unroll
        for (int i = 0; i < 4; i++) {
            const int rr = bm + wm + i * 16 + rbase;
#pragma unroll
            for (int r = 0; r < 4; r++) {
                const float v = acc[i][j][r] + bv;
                const int m = rr + r;
                if (OUT_MODE == 0) {
                    ((float*)Cp)[(size_t)m * N + cc] = v;
                } else if (OUT_MODE == 1) {
                    ((ushort_t*)Cp)[(size_t)m * N + cc] = bfbits(v);
                } else {
                    // value head-major: [b][head][pix][32]
                    const int bb  = m / LEN_IN;
                    const int pix = m - bb * LEN_IN;
                    const int head = cc >> 5, ch = cc & 31;
                    ((ushort_t*)Cp)[((size_t)((bb * 8 + head) * LEN_IN + pix) << 5) + ch] = bfbits(v);
                }
            }
        }
    }
}

__global__ __launch_bounds__(256) void gemm_dual(
    const ushort_t* __restrict__ in_bf, const ushort_t* __restrict__ wvT,
    const float* __restrict__ b_val, ushort_t* __restrict__ value_bf,
    const ushort_t* __restrict__ q_bf, const ushort_t* __restrict__ woaT,
    const float* __restrict__ bias_oa, float* __restrict__ offattn)
{
    __shared__ ushort_t As[128 * 32];
    __shared__ ushort_t Bs[128 * 32];
    int blk = blockIdx.x;
    if (blk < 340) {
        const int bn = (blk & 1) * 128, bm = (blk >> 1) * 128;
        gemm_core<2>(in_bf, wvT, b_val, value_bf, 256, bm, bn, As, Bs);
    } else {
        blk -= 340;
        const int bn = (blk % 3) * 128, bm = (blk / 3) * 128;
        gemm_core<0>(q_bf, woaT, bias_oa, offattn, 384, bm, bn, As, Bs);
    }
}

__global__ __launch_bounds__(256) void gemm_out(
    const ushort_t* __restrict__ mid_bf, const ushort_t* __restrict__ woutT,
    const float* __restrict__ b_out, float* __restrict__ out)
{
    __shared__ ushort_t As[128 * 32];
    __shared__ ushort_t Bs[128 * 32];
    const int bn = (blockIdx.x & 1) * 128, bm = (blockIdx.x >> 1) * 128;
    gemm_core<0>(mid_bf, woutT, b_out, out, 256, bm, bn, As, Bs);
}

// ======================= softmax + bilinear sampling v2 =======================
// value head-major [b][h][pix][32]. Block = 64 queries x 1 (b,h); 4 lanes per
// query split LEVELS (each lane: 4 points x all 32 channels). XCD-pinned so the
// 348 KB (b,h) value slice stays L2-resident. Channel reduction via wave-local
// LDS exchange (producer lanes are in the same wave -> no barrier).
__device__ __forceinline__ void accd(f32x2& a, unsigned u, f32x2 w) {
    f32x2 v;
    v.x = __uint_as_float(u << 16);
    v.y = __uint_as_float(u & 0xFFFF0000u);
    a = w * v + a;   // ffp-contract -> v_pk_fma_f32
}
__device__ __forceinline__ void acc_corner(f32x2* a, uint4 A, uint4 B, uint4 C, uint4 D, float wf) {
    const f32x2 w = {wf, wf};
    accd(a[0],  A.x, w); accd(a[1],  A.y, w); accd(a[2],  A.z, w); accd(a[3],  A.w, w);
    accd(a[4],  B.x, w); accd(a[5],  B.y, w); accd(a[6],  B.z, w); accd(a[7],  B.w, w);
    accd(a[8],  C.x, w); accd(a[9],  C.y, w); accd(a[10], C.z, w); accd(a[11], C.w, w);
    accd(a[12], D.x, w); accd(a[13], D.y, w); accd(a[14], D.z, w); accd(a[15], D.w, w);
}

__global__ __launch_bounds__(256) void msda_sample_v2(
    const ushort_t* __restrict__ value,   // [B*8][5440][32] bf16
    const float* __restrict__ refp,
    const float* __restrict__ offattn,
    ushort_t* __restrict__ mid)
{
    __shared__ float4 part[8][256];       // 32 KB

    const int tid = threadIdx.x;
    const unsigned bid = blockIdx.x;
    // XCD-pinned slice mapping: 85 q-chunks per (b,h), 4 (b,h) per XCD
    const int xcd   = bid & 7;
    const int pos   = bid >> 3;           // 0..339
    const int slice = pos / 85;           // 0..3
    const int qc    = pos - slice * 85;   // 0..84
    const int bh    = xcd * 4 + slice;    // 0..31
    const int b     = bh >> 3, h = bh & 7;

    const int ql = tid >> 2;              // 0..63
    const int pl = tid & 3;               // level owned by this lane
    const int q  = qc * 64 + ql;
    const int bq = b * LEN_Q + q;

    const int   shift = 6 - pl;           // log2(W), W = 64,32,16,8
    const int   W     = 1 << shift;
    const float fW    = (float)W;
    const float invW  = __uint_as_float((unsigned)(127 - shift) << 23);  // exact 2^-shift
    const int   st    = (pl == 0) ? 0 : (pl == 1) ? 4096 : (pl == 2) ? 5120 : 5376;

    const float2 rr2 = *(const float2*)(refp + (size_t)bq * 8 + pl * 2);
    const float* oab = offattn + (size_t)bq * 384;
    const float4 o01 = *(const float4*)(oab + h * 32 + pl * 8);
    const float4 o23 = *(const float4*)(oab + h * 32 + pl * 8 + 4);
    const float4 lg  = *(const float4*)(oab + 256 + h * 16 + pl * 4);

    float mx = fmaxf(fmaxf(lg.x, lg.y), fmaxf(lg.z, lg.w));
    mx = fmaxf(mx, __shfl_xor(mx, 1));
    mx = fmaxf(mx, __shfl_xor(mx, 2));

    const char* vbc = (const char*)(value + (size_t)bh * (LEN_IN * 32));

    f32x2 acc2[16];
#pragma unroll
    for (int d = 0; d < 16; d++) acc2[d] = (f32x2){0.f, 0.f};
    float esum = 0.f;

    const float oxA[4] = {o01.x, o01.z, o23.x, o23.z};
    const float oyA[4] = {o01.y, o01.w, o23.y, o23.w};
    const float lgA[4] = {lg.x, lg.y, lg.z, lg.w};

#pragma unroll
    for (int p = 0; p < 4; p++) {
        const float x = (rr2.x + oxA[p] * invW) * fW - 0.5f;
        const float y = (rr2.y + oyA[p] * invW) * fW - 0.5f;
        const float x0f = floorf(x), y0f = floorf(y);
        const float wx = x - x0f, wy = y - y0f;
        const int ix0 = (int)x0f, iy0 = (int)y0f;
        const int ix1 = ix0 + 1,  iy1 = iy0 + 1;
        const float vx0 = (ix0 >= 0 && ix0 < W) ? 1.f : 0.f;
        const float vx1 = (ix1 >= 0 && ix1 < W) ? 1.f : 0.f;
        const float vy0 = (iy0 >= 0 && iy0 < W) ? 1.f : 0.f;
        const float vy1 = (iy1 >= 0 && iy1 < W) ? 1.f : 0.f;
        const int cx0 = min(max(ix0, 0), W - 1);
        const int cx1 = min(max(ix1, 0), W - 1);
        const int cy0 = min(max(iy0, 0), W - 1);
        const int cy1 = min(max(iy1, 0), W - 1);
        const float hx0 = (1.f - wx) * vx0, hx1 = wx * vx1;
        const float hy0 = (1.f - wy) * vy0, hy1 = wy * vy1;

        const float e = __expf(lgA[p] - mx);
        esum += e;
        const float w00 = e * hx0 * hy0, w01 = e * hx1 * hy0;
        const float w10 = e * hx0 * hy1, w11 = e * hx1 * hy1;

        const int r0 = st + (cy0 << shift), r1 = st + (cy1 << shift);
        const uint4* c00 = (const uint4*)(vbc + ((size_t)(r0 + cx0) << 6));
        const uint4* c01 = (const uint4*)(vbc + ((size_t)(r0 + cx1) << 6));
        const uint4* c10 = (const uint4*)(vbc + ((size_t)(r1 + cx0) << 6));
        const uint4* c11 = (const uint4*)(vbc + ((size_t)(r1 + cx1) << 6));
        uint4 A0 = c00[0], A1 = c00[1], A2 = c00[2], A3 = c00[3];
        uint4 B0 = c01[0], B1 = c01[1], B2 = c01[2], B3 = c01[3];
        uint4 C0 = c10[0], C1 = c10[1], C2 = c10[2], C3 = c10[3];
        uint4 D0 = c11[0], D1 = c11[1], D2 = c11[2], D3 = c11[3];

        acc_corner(acc2, A0, A1, A2, A3, w00);
        acc_corner(acc2, B0, B1, B2, B3, w01);
        acc_corner(acc2, C0, C1, C2, C3, w10);
        acc_corner(acc2, D0, D1, D2, D3, w11);
    }

    // softmax denominator across the 4 level-lanes
    esum += __shfl_xor(esum, 1);
    esum += __shfl_xor(esum, 2);

    // channel reduction: wave-local LDS exchange
#pragma unroll
    for (int j = 0; j < 8; j++)
        part[j][tid] = make_float4(acc2[2 * j].x, acc2[2 * j].y,
                                   acc2[2 * j + 1].x, acc2[2 * j + 1].y);

    const int j0 = pl * 2;
    const int lb = tid & ~3;
    float4 s0 = part[j0][lb], s1 = part[j0 + 1][lb];
#pragma unroll
    for (int pp = 1; pp < 4; pp++) {
        const float4 t0 = part[j0][lb + pp];
        const float4 t1 = part[j0 + 1][lb + pp];
        s0.x += t0.x; s0.y += t0.y; s0.z += t0.z; s0.w += t0.w;
        s1.x += t1.x; s1.y += t1.y; s1.z += t1.z; s1.w += t1.w;
    }

    const float inv = 1.f / esum;
    uint4 o;
    o.x = pk2(s0.x * inv, s0.y * inv);
    o.y = pk2(s0.z * inv, s0.w * inv);
    o.z = pk2(s1.x * inv, s1.y * inv);
    o.w = pk2(s1.z * inv, s1.w * inv);
    *(uint4*)(mid + (size_t)bq * 256 + h * 32 + pl * 8) = o;
}

// ======================= launch =======================
extern "C" void kernel_launch(void* const* d_in, const int* in_sizes, int n_in,
                              void* d_out, int out_size, void* d_ws, size_t ws_size,
                              hipStream_t stream)
{
    const float* query  = (const float*)d_in[0];
    const float* refp   = (const float*)d_in[1];
    const float* inflat = (const float*)d_in[2];
    const float* W_val  = (const float*)d_in[5];
    const float* b_val  = (const float*)d_in[6];
    const float* W_off  = (const float*)d_in[7];
    const float* W_attn = (const float*)d_in[9];
    const float* b_off  = (const float*)d_in[8];
    const float* b_attn = (const float*)d_in[10];
    const float* W_out  = (const float*)d_in[11];
    const float* b_out  = (const float*)d_in[12];
    float* out = (float*)d_out;

    char* ws = (char*)d_ws;
    ushort_t* in_bf    = (ushort_t*)ws;                               // reused as mid_bf
    ushort_t* q_bf     = (ushort_t*)(ws + 11141120);
    ushort_t* value_bf = (ushort_t*)(ws + 22282240);                  // head-major layout
    ushort_t* wvT      = (ushort_t*)(ws + 33423360);
    ushort_t* woutT    = (ushort_t*)(ws + 33554432);
    ushort_t* woaT     = (ushort_t*)(ws + 33685504);
    float*    bias_oa  = (float*)   (ws + 33882112);
    float*    offattn  = (float*)   (ws + 33883648);
    ushort_t* mid_bf   = in_bf;

    dim3 blk(256);
    pack_inputs<<<dim3(5553), blk, 0, stream>>>(
        inflat, query, W_val, W_off, W_attn, W_out, b_off, b_attn,
        in_bf, q_bf, wvT, woaT, woutT, bias_oa);
    gemm_dual<<<dim3(850), blk, 0, stream>>>(
        in_bf, wvT, b_val, value_bf, q_bf, woaT, bias_oa, offattn);
    msda_sample_v2<<<dim3(2720), blk, 0, stream>>>(
        value_bf, refp, offattn, mid_bf);
    gemm_out<<<dim3(340), blk, 0, stream>>>(
        mid_bf, woutT, b_out, out);
}

// Round 2
// 195.920 us; speedup vs baseline: 1.1002x; 1.1002x over previous
//
#include <hip/hip_runtime.h>
#include <hip/hip_bf16.h>
#include <math.h>

typedef unsigned short ushort_t;
typedef __attribute__((ext_vector_type(8))) short bf16x8;
typedef __attribute__((ext_vector_type(4))) float f32x4;
typedef __attribute__((ext_vector_type(2))) float f32x2;

constexpr int BATCH   = 4;
constexpr int D_MODEL = 256;
constexpr int LEN_IN  = 5440;
constexpr int LEN_Q   = 5440;
constexpr int M_TOT   = BATCH * LEN_Q;   // 21760

#define ASG __attribute__((address_space(1)))
#define ASL __attribute__((address_space(3)))

__device__ __forceinline__ void gld16(const void* g, void* l) {
    __builtin_amdgcn_global_load_lds((ASG const void*)g, (ASL void*)l, 16, 0, 0);
}

__device__ __forceinline__ ushort_t bfbits(float x) {
    __hip_bfloat16 h = __float2bfloat16(x);
    ushort_t u; __builtin_memcpy(&u, &h, 2); return u;
}
__device__ __forceinline__ unsigned pk2(float a, float b) {
    return (unsigned)bfbits(a) | ((unsigned)bfbits(b) << 16);
}

// ======================= pack / convert / transpose =======================
__global__ __launch_bounds__(256) void pack_inputs(
    const float* __restrict__ inflat, const float* __restrict__ query,
    const float* __restrict__ Wv, const float* __restrict__ Wo,
    const float* __restrict__ Wa, const float* __restrict__ Wout,
    const float* __restrict__ b_off, const float* __restrict__ b_attn,
    ushort_t* __restrict__ in_bf, ushort_t* __restrict__ q_bf,
    ushort_t* __restrict__ wvT, ushort_t* __restrict__ woaT,
    ushort_t* __restrict__ woutT, float* __restrict__ bias_oa)
{
    const int blk = blockIdx.x, tid = threadIdx.x;
    if (blk < 5440) {
        const float* src = (blk < 2720) ? inflat : query;
        ushort_t*    dst = (blk < 2720) ? in_bf : q_bf;
        const int rb = (blk < 2720) ? blk : blk - 2720;
        const size_t base = (size_t)rb * 2048 + tid * 8;
        float4 a = *(const float4*)(src + base);
        float4 b = *(const float4*)(src + base + 4);
        uint4 o;
        o.x = pk2(a.x, a.y); o.y = pk2(a.z, a.w);
        o.z = pk2(b.x, b.y); o.w = pk2(b.z, b.w);
        *(uint4*)(dst + base) = o;
    } else if (blk < 5504) {
        const float* src = (blk < 5472) ? Wv : Wout;
        ushort_t*    dst = (blk < 5472) ? wvT : woutT;
        const int base = (blk - ((blk < 5472) ? 5440 : 5472)) * 2048;
#pragma unroll
        for (int i = 0; i < 8; i++) {
            const int idx = base + i * 256 + tid;
            const int k = idx >> 8, n = idx & 255;
            dst[n * 256 + k] = bfbits(src[idx]);
        }
    } else if (blk < 5552) {
        const int base = (blk - 5504) * 2048;
#pragma unroll
        for (int i = 0; i < 8; i++) {
            const int idx = base + i * 256 + tid;   // < 98304
            const int k = idx / 384, j = idx - k * 384;
            const float v = (j < 256) ? Wo[k * 256 + j] : Wa[k * 128 + (j - 256)];
            woaT[j * 256 + k] = bfbits(v);
        }
    } else {
        bias_oa[tid] = b_off[tid];
        if (tid < 128) bias_oa[256 + tid] = b_attn[tid];
    }
}

// ======================= bf16 MFMA GEMM core =======================
// OUT_MODE: 0 = f32 row-major, 1 = bf16 row-major, 2 = bf16 head-major value
template <int OUT_MODE>
__device__ __forceinline__ void gemm_core(
    const ushort_t* __restrict__ A, const ushort_t* __restrict__ BT,
    const float* __restrict__ bias, void* __restrict__ Cp, int N,
    int bm, int bn, ushort_t* As, ushort_t* Bs)
{
    const int tid  = threadIdx.x;
    const int wave = tid >> 6, lane = tid & 63;
    const int wm = (wave >> 1) * 64, wn = (wave & 1) * 64;
    const int c0 = 2 * wave, c1 = 2 * wave + 1;
    const int kb = (lane & 3) * 8;
    const ushort_t* gA0 = A  + (size_t)(bm + c0 * 16 + (lane >> 2)) * 256 + kb;
    const ushort_t* gA1 = A  + (size_t)(bm + c1 * 16 + (lane >> 2)) * 256 + kb;
    const ushort_t* gB0 = BT + (size_t)(bn + c0 * 16 + (lane >> 2)) * 256 + kb;
    const ushort_t* gB1 = BT + (size_t)(bn + c1 * 16 + (lane >> 2)) * 256 + kb;
    ushort_t* lA0 = As + c0 * 512;
    ushort_t* lA1 = As + c1 * 512;
    ushort_t* lB0 = Bs + c0 * 512;
    ushort_t* lB1 = Bs + c1 * 512;

    f32x4 acc[4][4] = {};

    const int row = lane & 15, kg = (lane >> 4) * 8;
    for (int kt = 0; kt < 8; kt++) {
        gld16(gA0, lA0); gld16(gA1, lA1);
        gld16(gB0, lB0); gld16(gB1, lB1);
        gA0 += 32; gA1 += 32; gB0 += 32; gB1 += 32;
        __syncthreads();
        bf16x8 af[4], bfr[4];
#pragma unroll
        for (int i = 0; i < 4; i++)
            af[i] = *(const bf16x8*)(As + (wm + i * 16 + row) * 32 + kg);
#pragma unroll
        for (int j = 0; j < 4; j++)
            bfr[j] = *(const bf16x8*)(Bs + (wn + j * 16 + row) * 32 + kg);
#pragma unroll
        for (int i = 0; i < 4; i++)
#pragma unroll
            for (int j = 0; j < 4; j++)
                acc[i][j] = __builtin_amdgcn_mfma_f32_16x16x32_bf16(
                    af[i], bfr[j], acc[i][j], 0, 0, 0);
        __syncthreads();
    }

    const int col = lane & 15, rbase = (lane >> 4) * 4;
#pragma unroll
    for (int j = 0; j < 4; j++) {
        const int cc = bn + wn + j * 16 + col;
        const float bv = bias[cc];
#pragma unroll
        for (int i = 0; i < 4; i++) {
            const int rr = bm + wm + i * 16 + rbase;
#pragma unroll
            for (int r = 0; r < 4; r++) {
                const float v = acc[i][j][r] + bv;
                const int m = rr + r;
                if (OUT_MODE == 0) {
                    ((float*)Cp)[(size_t)m * N + cc] = v;
                } else if (OUT_MODE == 1) {
                    ((ushort_t*)Cp)[(size_t)m * N + cc] = bfbits(v);
                } else {
                    // value head-major: [b][head][pix][32]
                    const int bb  = m / LEN_IN;
                    const int pix = m - bb * LEN_IN;
                    const int head = cc >> 5, ch = cc & 31;
                    ((ushort_t*)Cp)[((size_t)((bb * 8 + head) * LEN_IN + pix) << 5) + ch] = bfbits(v);
                }
            }
        }
    }
}

__global__ __launch_bounds__(256) void gemm_dual(
    const ushort_t* __restrict__ in_bf, const ushort_t* __restrict__ wvT,
    const float* __restrict__ b_val, ushort_t* __restrict__ value_bf,
    const ushort_t* __restrict__ q_bf, const ushort_t* __restrict__ woaT,
    const float* __restrict__ bias_oa, float* __restrict__ offattn)
{
    __shared__ ushort_t As[128 * 32];
    __shared__ ushort_t Bs[128 * 32];
    int blk = blockIdx.x;
    if (blk < 340) {
        const int bn = (blk & 1) * 128, bm = (blk >> 1) * 128;
        gemm_core<2>(in_bf, wvT, b_val, value_bf, 256, bm, bn, As, Bs);
    } else {
        blk -= 340;
        const int bn = (blk % 3) * 128, bm = (blk / 3) * 128;
        gemm_core<0>(q_bf, woaT, bias_oa, offattn, 384, bm, bn, As, Bs);
    }
}

__global__ __launch_bounds__(256) void gemm_out(
    const ushort_t* __restrict__ mid_bf, const ushort_t* __restrict__ woutT,
    const float* __restrict__ b_out, float* __restrict__ out)
{
    __shared__ ushort_t As[128 * 32];
    __shared__ ushort_t Bs[128 * 32];
    const int bn = (blockIdx.x & 1) * 128, bm = (blockIdx.x >> 1) * 128;
    gemm_core<0>(mid_bf, woutT, b_out, out, 256, bm, bn, As, Bs);
}

// ======================= softmax + bilinear sampling v3 =======================
// value head-major [b][h][pix][32] bf16, XCD-pinned (b,h) slices (348 KB, fits
// the 4 MiB per-XCD L2).  Block = 64 queries x 1 (b,h); each query served by
// 4 channel-split lanes (8 ch = 16 B each) -> every corner is fetched as 4
// CONTIGUOUS 16 B lane-loads (one 64 B segment per 4 lanes, x-neighbor corners
// share a 128 B line).  Coord math duplicated 4x (VALU has headroom); no LDS.
__device__ __forceinline__ void accd(f32x2& a, unsigned u, f32x2 w) {
    f32x2 v;
    v.x = __uint_as_float(u << 16);
    v.y = __uint_as_float(u & 0xFFFF0000u);
    a = w * v + a;   // ffp-contract -> v_pk_fma_f32
}
__device__ __forceinline__ void accp(f32x2* a, uint4 u, float wf) {
    const f32x2 w = {wf, wf};
    accd(a[0], u.x, w); accd(a[1], u.y, w);
    accd(a[2], u.z, w); accd(a[3], u.w, w);
}

__global__ __launch_bounds__(256) void msda_sample_v3(
    const ushort_t* __restrict__ value,   // [B*8][5440][32] bf16
    const float* __restrict__ refp,
    const float* __restrict__ offattn,
    ushort_t* __restrict__ mid)
{
    const int tid = threadIdx.x;
    const unsigned bid = blockIdx.x;
    // XCD-pinned slice mapping: 85 q-chunks per (b,h), 4 (b,h) per XCD
    const int xcd   = bid & 7;
    const int pos   = bid >> 3;           // 0..339
    const int slice = pos / 85;           // 0..3
    const int qc    = pos - slice * 85;   // 0..84
    const int bh    = xcd * 4 + slice;    // 0..31
    const int b     = bh >> 3, h = bh & 7;

    const int ql = tid >> 2;              // 0..63
    const int cg = tid & 3;               // channel group (8 ch = 16 B)
    const int bq = b * LEN_Q + qc * 64 + ql;

    const float* oab = offattn + (size_t)bq * 384;
    // logits for this head
    const float* lp = oab + 256 + h * 16;
    float4 l0 = ((const float4*)lp)[0];
    float4 l1 = ((const float4*)lp)[1];
    float4 l2 = ((const float4*)lp)[2];
    float4 l3 = ((const float4*)lp)[3];
    float lg[16] = {l0.x, l0.y, l0.z, l0.w, l1.x, l1.y, l1.z, l1.w,
                    l2.x, l2.y, l2.z, l2.w, l3.x, l3.y, l3.z, l3.w};
    float mx = lg[0];
#pragma unroll
    for (int j = 1; j < 16; j++) mx = fmaxf(mx, lg[j]);

    // offsets for this head
    const float* op = oab + h * 32;
    float4 ov[8];
#pragma unroll
    for (int j = 0; j < 8; j++) ov[j] = ((const float4*)op)[j];
    const float* rp = refp + (size_t)bq * 8;
    float4 r0 = ((const float4*)rp)[0];
    float4 r1 = ((const float4*)rp)[1];
    const float rx[4] = {r0.x, r0.z, r1.x, r1.z};
    const float ry[4] = {r0.y, r0.w, r1.y, r1.w};

    // lane's 16 B channel slice inside each 64 B corner block
    const char* vb = (const char*)value + (size_t)bh * (LEN_IN * 64) + cg * 16;

    f32x2 acc2[4];
#pragma unroll
    for (int d = 0; d < 4; d++) acc2[d] = (f32x2){0.f, 0.f};
    float esum = 0.f;

#pragma unroll
    for (int l = 0; l < 4; l++) {
        const int   shift = 6 - l;        // log2(W), W = 64,32,16,8 (square)
        const int   W     = 1 << shift;
        const float fW    = (float)W;
        const float invW  = __uint_as_float((unsigned)(127 - shift) << 23); // exact 2^-shift
        const int   st    = (l == 0) ? 0 : (l == 1) ? 4096 : (l == 2) ? 5120 : 5376;
#pragma unroll
        for (int p = 0; p < 4; p++) {
            const float* o2 = &ov[l * 2].x;
            const float ox = o2[p * 2 + 0];
            const float oy = o2[p * 2 + 1];
            const float x = (rx[l] + ox * invW) * fW - 0.5f;
            const float y = (ry[l] + oy * invW) * fW - 0.5f;
            const float x0f = floorf(x), y0f = floorf(y);
            const float wx = x - x0f, wy = y - y0f;
            const int ix0 = (int)x0f, iy0 = (int)y0f;
            const int ix1 = ix0 + 1,  iy1 = iy0 + 1;
            const float vx0 = (ix0 >= 0 && ix0 < W) ? 1.f : 0.f;
            const float vx1 = (ix1 >= 0 && ix1 < W) ? 1.f : 0.f;
            const float vy0 = (iy0 >= 0 && iy0 < W) ? 1.f : 0.f;
            const float vy1 = (iy1 >= 0 && iy1 < W) ? 1.f : 0.f;
            const int cx0 = min(max(ix0, 0), W - 1);
            const int cx1 = min(max(ix1, 0), W - 1);
            const int cy0 = min(max(iy0, 0), W - 1);
            const int cy1 = min(max(iy1, 0), W - 1);
            const float hx0 = (1.f - wx) * vx0, hx1 = wx * vx1;
            const float hy0 = (1.f - wy) * vy0, hy1 = wy * vy1;

            const float e = __expf(lg[l * 4 + p] - mx);
            esum += e;
            const float w00 = e * hx0 * hy0, w01 = e * hx1 * hy0;
            const float w10 = e * hx0 * hy1, w11 = e * hx1 * hy1;

            const int r0a = st + (cy0 << shift);
            const int r1a = st + (cy1 << shift);
            uint4 v00 = *(const uint4*)(vb + ((size_t)(r0a + cx0) << 6));
            uint4 v01 = *(const uint4*)(vb + ((size_t)(r0a + cx1) << 6));
            uint4 v10 = *(const uint4*)(vb + ((size_t)(r1a + cx0) << 6));
            uint4 v11 = *(const uint4*)(vb + ((size_t)(r1a + cx1) << 6));

            accp(acc2, v00, w00);
            accp(acc2, v01, w01);
            accp(acc2, v10, w10);
            accp(acc2, v11, w11);
        }
    }

    const float inv = 1.f / esum;
    uint4 o;
    o.x = pk2(acc2[0].x * inv, acc2[0].y * inv);
    o.y = pk2(acc2[1].x * inv, acc2[1].y * inv);
    o.z = pk2(acc2[2].x * inv, acc2[2].y * inv);
    o.w = pk2(acc2[3].x * inv, acc2[3].y * inv);
    ((uint4*)(mid + (size_t)bq * 256 + h * 32))[cg] = o;
}

// ======================= launch =======================
extern "C" void kernel_launch(void* const* d_in, const int* in_sizes, int n_in,
                              void* d_out, int out_size, void* d_ws, size_t ws_size,
                              hipStream_t stream)
{
    const float* query  = (const float*)d_in[0];
    const float* refp   = (const float*)d_in[1];
    const float* inflat = (const float*)d_in[2];
    const float* W_val  = (const float*)d_in[5];
    const float* b_val  = (const float*)d_in[6];
    const float* W_off  = (const float*)d_in[7];
    const float* W_attn = (const float*)d_in[9];
    const float* b_off  = (const float*)d_in[8];
    const float* b_attn = (const float*)d_in[10];
    const float* W_out  = (const float*)d_in[11];
    const float* b_out  = (const float*)d_in[12];
    float* out = (float*)d_out;

    char* ws = (char*)d_ws;
    ushort_t* in_bf    = (ushort_t*)ws;                               // reused as mid_bf
    ushort_t* q_bf     = (ushort_t*)(ws + 11141120);
    ushort_t* value_bf = (ushort_t*)(ws + 22282240);                  // head-major layout
    ushort_t* wvT      = (ushort_t*)(ws + 33423360);
    ushort_t* woutT    = (ushort_t*)(ws + 33554432);
    ushort_t* woaT     = (ushort_t*)(ws + 33685504);
    float*    bias_oa  = (float*)   (ws + 33882112);
    float*    offattn  = (float*)   (ws + 33883648);
    ushort_t* mid_bf   = in_bf;

    dim3 blk(256);
    pack_inputs<<<dim3(5553), blk, 0, stream>>>(
        inflat, query, W_val, W_off, W_attn, W_out, b_off, b_attn,
        in_bf, q_bf, wvT, woaT, woutT, bias_oa);
    gemm_dual<<<dim3(850), blk, 0, stream>>>(
        in_bf, wvT, b_val, value_bf, q_bf, woaT, bias_oa, offattn);
    msda_sample_v3<<<dim3(2720), blk, 0, stream>>>(
        value_bf, refp, offattn, mid_bf);
    gemm_out<<<dim3(340), blk, 0, stream>>>(
        mid_bf, woutT, b_out, out);
}

// Round 3
// 184.033 us; speedup vs baseline: 1.1712x; 1.0646x over previous
//
#include <hip/hip_runtime.h>
#include <hip/hip_bf16.h>
#include <math.h>

typedef unsigned short ushort_t;
typedef __attribute__((ext_vector_type(8))) short bf16x8;
typedef __attribute__((ext_vector_type(4))) float f32x4;
typedef __attribute__((ext_vector_type(2))) float f32x2;

constexpr int BATCH   = 4;
constexpr int D_MODEL = 256;
constexpr int LEN_IN  = 5440;
constexpr int LEN_Q   = 5440;
constexpr int M_TOT   = BATCH * LEN_Q;   // 21760

#define ASG __attribute__((address_space(1)))
#define ASL __attribute__((address_space(3)))

__device__ __forceinline__ void gld16(const void* g, void* l) {
    __builtin_amdgcn_global_load_lds((ASG const void*)g, (ASL void*)l, 16, 0, 0);
}

__device__ __forceinline__ ushort_t bfbits(float x) {
    __hip_bfloat16 h = __float2bfloat16(x);
    ushort_t u; __builtin_memcpy(&u, &h, 2); return u;
}
__device__ __forceinline__ unsigned pk2(float a, float b) {
    return (unsigned)bfbits(a) | ((unsigned)bfbits(b) << 16);
}

// ======================= weight prep (tiny) =======================
// blk 0..31  : Wv  [256k][256n] -> wvT  [n][k] bf16   (8 k-rows per block)
// blk 32..63 : Wout             -> woutT
// blk 64..95 : Wo|Wa [256k][384j] -> woaT [j][k] bf16
// blk 96     : bias concat
// Thread t's output row (col t of the source) is exactly what its coalesced
// column reads fetch -> registers only, no LDS, 16 B vector stores.
__global__ __launch_bounds__(256) void pack_weights(
    const float* __restrict__ Wv, const float* __restrict__ Wout,
    const float* __restrict__ Wo, const float* __restrict__ Wa,
    const float* __restrict__ b_off, const float* __restrict__ b_attn,
    ushort_t* __restrict__ wvT, ushort_t* __restrict__ woutT,
    ushort_t* __restrict__ woaT, float* __restrict__ bias_oa)
{
    const int blk = blockIdx.x, t = threadIdx.x;
    if (blk < 64) {
        const float* src = (blk < 32) ? Wv : Wout;
        ushort_t*    dst = (blk < 32) ? wvT : woutT;
        const int k0 = (blk & 31) * 8;
        float f[8];
#pragma unroll
        for (int i = 0; i < 8; i++) f[i] = src[(k0 + i) * 256 + t];
        *(uint4*)(dst + t * 256 + k0) =
            make_uint4(pk2(f[0], f[1]), pk2(f[2], f[3]),
                       pk2(f[4], f[5]), pk2(f[6], f[7]));
    } else if (blk < 96) {
        const int k0 = (blk - 64) * 8;
#pragma unroll
        for (int rep = 0; rep < 2; rep++) {
            const int j = (rep == 0) ? t : 256 + t;
            if (rep == 1 && t >= 128) break;
            float f[8];
#pragma unroll
            for (int i = 0; i < 8; i++)
                f[i] = (j < 256) ? Wo[(k0 + i) * 256 + j]
                                 : Wa[(k0 + i) * 128 + (j - 256)];
            *(uint4*)(woaT + j * 256 + k0) =
                make_uint4(pk2(f[0], f[1]), pk2(f[2], f[3]),
                           pk2(f[4], f[5]), pk2(f[6], f[7]));
        }
    } else {
        bias_oa[t] = b_off[t];
        if (t < 128) bias_oa[256 + t] = b_attn[t];
    }
}

// ======================= bf16 MFMA GEMM core =======================
// OUT_MODE: 0 = f32 row-major, 2 = bf16 head-major value
// A_F32: A operand is raw f32; reg-stage (float4 x2 -> cvt_pk_bf16 ->
//        ds_write_b128) into the SAME LDS layout gld16 produces.
template <int OUT_MODE, bool A_F32>
__device__ __forceinline__ void gemm_core(
    const void* __restrict__ Ap, const ushort_t* __restrict__ BT,
    const float* __restrict__ bias, void* __restrict__ Cp, int N,
    int bm, int bn, ushort_t* As, ushort_t* Bs)
{
    const int tid  = threadIdx.x;
    const int wave = tid >> 6, lane = tid & 63;
    const int wm = (wave >> 1) * 64, wn = (wave & 1) * 64;
    const int c0 = 2 * wave, c1 = 2 * wave + 1;
    const int kb = (lane & 3) * 8;
    const int ar0 = bm + c0 * 16 + (lane >> 2);
    const int ar1 = bm + c1 * 16 + (lane >> 2);
    const ushort_t* gA0h = nullptr; const ushort_t* gA1h = nullptr;
    const float*    gA0f = nullptr; const float*    gA1f = nullptr;
    if (A_F32) {
        gA0f = (const float*)Ap + (size_t)ar0 * 256 + kb;
        gA1f = (const float*)Ap + (size_t)ar1 * 256 + kb;
    } else {
        gA0h = (const ushort_t*)Ap + (size_t)ar0 * 256 + kb;
        gA1h = (const ushort_t*)Ap + (size_t)ar1 * 256 + kb;
    }
    const ushort_t* gB0 = BT + (size_t)(bn + c0 * 16 + (lane >> 2)) * 256 + kb;
    const ushort_t* gB1 = BT + (size_t)(bn + c1 * 16 + (lane >> 2)) * 256 + kb;
    ushort_t* lA0 = As + c0 * 512;   // wave-uniform chunk base
    ushort_t* lA1 = As + c1 * 512;
    ushort_t* lB0 = Bs + c0 * 512;
    ushort_t* lB1 = Bs + c1 * 512;

    f32x4 acc[4][4] = {};
    const int row = lane & 15, kg = (lane >> 4) * 8;
    for (int kt = 0; kt < 8; kt++) {
        if (A_F32) {
            float4 a0 = *(const float4*)gA0f;
            float4 a1 = *(const float4*)(gA0f + 4);
            float4 b0 = *(const float4*)gA1f;
            float4 b1 = *(const float4*)(gA1f + 4);
            *(uint4*)(lA0 + lane * 8) =
                make_uint4(pk2(a0.x, a0.y), pk2(a0.z, a0.w),
                           pk2(a1.x, a1.y), pk2(a1.z, a1.w));
            *(uint4*)(lA1 + lane * 8) =
                make_uint4(pk2(b0.x, b0.y), pk2(b0.z, b0.w),
                           pk2(b1.x, b1.y), pk2(b1.z, b1.w));
            gA0f += 32; gA1f += 32;
        } else {
            gld16(gA0h, lA0); gld16(gA1h, lA1);
            gA0h += 32; gA1h += 32;
        }
        gld16(gB0, lB0); gld16(gB1, lB1);
        gB0 += 32; gB1 += 32;
        __syncthreads();
        bf16x8 af[4], bfr[4];
#pragma unroll
        for (int i = 0; i < 4; i++)
            af[i] = *(const bf16x8*)(As + (wm + i * 16 + row) * 32 + kg);
#pragma unroll
        for (int j = 0; j < 4; j++)
            bfr[j] = *(const bf16x8*)(Bs + (wn + j * 16 + row) * 32 + kg);
#pragma unroll
        for (int i = 0; i < 4; i++)
#pragma unroll
            for (int j = 0; j < 4; j++)
                acc[i][j] = __builtin_amdgcn_mfma_f32_16x16x32_bf16(
                    af[i], bfr[j], acc[i][j], 0, 0, 0);
        __syncthreads();
    }

    const int col = lane & 15, rbase = (lane >> 4) * 4;
#pragma unroll
    for (int j = 0; j < 4; j++) {
        const int cc = bn + wn + j * 16 + col;
        const float bv = bias[cc];
#pragma unroll
        for (int i = 0; i < 4; i++) {
            const int rr = bm + wm + i * 16 + rbase;
#pragma unroll
            for (int r = 0; r < 4; r++) {
                const float v = acc[i][j][r] + bv;
                const int m = rr + r;
                if (OUT_MODE == 0) {
                    ((float*)Cp)[(size_t)m * N + cc] = v;
                } else {
                    // value head-major: [b][head][pix][32]
                    const int bb  = m / LEN_IN;
                    const int pix = m - bb * LEN_IN;
                    const int head = cc >> 5, ch = cc & 31;
                    ((ushort_t*)Cp)[((size_t)((bb * 8 + head) * LEN_IN + pix) << 5) + ch] = bfbits(v);
                }
            }
        }
    }
}

__global__ __launch_bounds__(256) void gemm_dual(
    const float* __restrict__ inflat, const ushort_t* __restrict__ wvT,
    const float* __restrict__ b_val, ushort_t* __restrict__ value_bf,
    const float* __restrict__ query, const ushort_t* __restrict__ woaT,
    const float* __restrict__ bias_oa, float* __restrict__ offattn)
{
    __shared__ ushort_t As[128 * 32];
    __shared__ ushort_t Bs[128 * 32];
    int blk = blockIdx.x;
    if (blk < 340) {
        const int bn = (blk & 1) * 128, bm = (blk >> 1) * 128;
        gemm_core<2, true>(inflat, wvT, b_val, value_bf, 256, bm, bn, As, Bs);
    } else {
        blk -= 340;
        const int bn = (blk % 3) * 128, bm = (blk / 3) * 128;
        gemm_core<0, true>(query, woaT, bias_oa, offattn, 384, bm, bn, As, Bs);
    }
}

__global__ __launch_bounds__(256) void gemm_out(
    const ushort_t* __restrict__ mid_bf, const ushort_t* __restrict__ woutT,
    const float* __restrict__ b_out, float* __restrict__ out)
{
    __shared__ ushort_t As[128 * 32];
    __shared__ ushort_t Bs[128 * 32];
    const int bn = (blockIdx.x & 1) * 128, bm = (blockIdx.x >> 1) * 128;
    gemm_core<0, false>(mid_bf, woutT, b_out, out, 256, bm, bn, As, Bs);
}

// ======================= softmax + bilinear sampling v3b =======================
// value head-major [b][h][pix][32] bf16, XCD-pinned (b,h) slices (348 KB fits
// the 4 MiB per-XCD L2). Block = 64 queries x 1 (b,h); each query served by
// 4 channel-split lanes (8 ch = 16 B each). Offsets loaded per-level to cut
// VGPR pressure (more waves in flight for the gather latency).
__device__ __forceinline__ void accd(f32x2& a, unsigned u, f32x2 w) {
    f32x2 v;
    v.x = __uint_as_float(u << 16);
    v.y = __uint_as_float(u & 0xFFFF0000u);
    a = w * v + a;   // ffp-contract -> v_pk_fma_f32
}
__device__ __forceinline__ void accp(f32x2* a, uint4 u, float wf) {
    const f32x2 w = {wf, wf};
    accd(a[0], u.x, w); accd(a[1], u.y, w);
    accd(a[2], u.z, w); accd(a[3], u.w, w);
}

__global__ __launch_bounds__(256) void msda_sample_v3(
    const ushort_t* __restrict__ value,   // [B*8][5440][32] bf16
    const float* __restrict__ refp,
    const float* __restrict__ offattn,
    ushort_t* __restrict__ mid)
{
    const int tid = threadIdx.x;
    const unsigned bid = blockIdx.x;
    // XCD-pinned slice mapping: 85 q-chunks per (b,h), 4 (b,h) per XCD
    const int xcd   = bid & 7;
    const int pos   = bid >> 3;           // 0..339
    const int slice = pos / 85;           // 0..3
    const int qc    = pos - slice * 85;   // 0..84
    const int bh    = xcd * 4 + slice;    // 0..31
    const int b     = bh >> 3, h = bh & 7;

    const int ql = tid >> 2;              // 0..63
    const int cg = tid & 3;               // channel group (8 ch = 16 B)
    const int bq = b * LEN_Q + qc * 64 + ql;

    const float* oab = offattn + (size_t)bq * 384;
    // logits for this head
    const float* lp = oab + 256 + h * 16;
    float4 l0 = ((const float4*)lp)[0];
    float4 l1 = ((const float4*)lp)[1];
    float4 l2 = ((const float4*)lp)[2];
    float4 l3 = ((const float4*)lp)[3];
    float lg[16] = {l0.x, l0.y, l0.z, l0.w, l1.x, l1.y, l1.z, l1.w,
                    l2.x, l2.y, l2.z, l2.w, l3.x, l3.y, l3.z, l3.w};
    float mx = lg[0];
#pragma unroll
    for (int j = 1; j < 16; j++) mx = fmaxf(mx, lg[j]);

    const float* op = oab + h * 32;
    const float* rp = refp + (size_t)bq * 8;

    // lane's 16 B channel slice inside each 64 B corner block
    const char* vb = (const char*)value + (size_t)bh * (LEN_IN * 64) + cg * 16;

    f32x2 acc2[4];
#pragma unroll
    for (int d = 0; d < 4; d++) acc2[d] = (f32x2){0.f, 0.f};
    float esum = 0.f;

#pragma unroll
    for (int l = 0; l < 4; l++) {
        const int   shift = 6 - l;        // log2(W), W = 64,32,16,8 (square)
        const int   W     = 1 << shift;
        const float fW    = (float)W;
        const float invW  = __uint_as_float((unsigned)(127 - shift) << 23); // exact 2^-shift
        const int   st    = (l == 0) ? 0 : (l == 1) ? 4096 : (l == 2) ? 5120 : 5376;

        const float2 rl = *(const float2*)(rp + l * 2);
        const float4 oA = ((const float4*)op)[l * 2];
        const float4 oB = ((const float4*)op)[l * 2 + 1];
        const float oxA[4] = {oA.x, oA.z, oB.x, oB.z};
        const float oyA[4] = {oA.y, oA.w, oB.y, oB.w};
#pragma unroll
        for (int p = 0; p < 4; p++) {
            const float x = (rl.x + oxA[p] * invW) * fW - 0.5f;
            const float y = (rl.y + oyA[p] * invW) * fW - 0.5f;
            const float x0f = floorf(x), y0f = floorf(y);
            const float wx = x - x0f, wy = y - y0f;
            const int ix0 = (int)x0f, iy0 = (int)y0f;
            const int ix1 = ix0 + 1,  iy1 = iy0 + 1;
            const float vx0 = (ix0 >= 0 && ix0 < W) ? 1.f : 0.f;
            const float vx1 = (ix1 >= 0 && ix1 < W) ? 1.f : 0.f;
            const float vy0 = (iy0 >= 0 && iy0 < W) ? 1.f : 0.f;
            const float vy1 = (iy1 >= 0 && iy1 < W) ? 1.f : 0.f;
            const int cx0 = min(max(ix0, 0), W - 1);
            const int cx1 = min(max(ix1, 0), W - 1);
            const int cy0 = min(max(iy0, 0), W - 1);
            const int cy1 = min(max(iy1, 0), W - 1);
            const float hx0 = (1.f - wx) * vx0, hx1 = wx * vx1;
            const float hy0 = (1.f - wy) * vy0, hy1 = wy * vy1;

            const float e = __expf(lg[l * 4 + p] - mx);
            esum += e;
            const float w00 = e * hx0 * hy0, w01 = e * hx1 * hy0;
            const float w10 = e * hx0 * hy1, w11 = e * hx1 * hy1;

            const int r0a = st + (cy0 << shift);
            const int r1a = st + (cy1 << shift);
            uint4 v00 = *(const uint4*)(vb + ((size_t)(r0a + cx0) << 6));
            uint4 v01 = *(const uint4*)(vb + ((size_t)(r0a + cx1) << 6));
            uint4 v10 = *(const uint4*)(vb + ((size_t)(r1a + cx0) << 6));
            uint4 v11 = *(const uint4*)(vb + ((size_t)(r1a + cx1) << 6));

            accp(acc2, v00, w00);
            accp(acc2, v01, w01);
            accp(acc2, v10, w10);
            accp(acc2, v11, w11);
        }
    }

    const float inv = 1.f / esum;
    uint4 o;
    o.x = pk2(acc2[0].x * inv, acc2[0].y * inv);
    o.y = pk2(acc2[1].x * inv, acc2[1].y * inv);
    o.z = pk2(acc2[2].x * inv, acc2[2].y * inv);
    o.w = pk2(acc2[3].x * inv, acc2[3].y * inv);
    ((uint4*)(mid + (size_t)bq * 256 + h * 32))[cg] = o;
}

// ======================= launch =======================
extern "C" void kernel_launch(void* const* d_in, const int* in_sizes, int n_in,
                              void* d_out, int out_size, void* d_ws, size_t ws_size,
                              hipStream_t stream)
{
    const float* query  = (const float*)d_in[0];
    const float* refp   = (const float*)d_in[1];
    const float* inflat = (const float*)d_in[2];
    const float* W_val  = (const float*)d_in[5];
    const float* b_val  = (const float*)d_in[6];
    const float* W_off  = (const float*)d_in[7];
    const float* W_attn = (const float*)d_in[9];
    const float* b_off  = (const float*)d_in[8];
    const float* b_attn = (const float*)d_in[10];
    const float* W_out  = (const float*)d_in[11];
    const float* b_out  = (const float*)d_in[12];
    float* out = (float*)d_out;

    char* ws = (char*)d_ws;
    ushort_t* mid_bf   = (ushort_t*)ws;                               // 11,141,120
    ushort_t* value_bf = (ushort_t*)(ws + 11141120);                  // 11,141,120 head-major
    ushort_t* wvT      = (ushort_t*)(ws + 22282240);                  // 131,072
    ushort_t* woutT    = (ushort_t*)(ws + 22413312);                  // 131,072
    ushort_t* woaT     = (ushort_t*)(ws + 22544384);                  // 196,608
    float*    bias_oa  = (float*)   (ws + 22740992);                  // 1,536
    float*    offattn  = (float*)   (ws + 22742528);                  // 33,423,360

    dim3 blk(256);
    pack_weights<<<dim3(97), blk, 0, stream>>>(
        W_val, W_out, W_off, W_attn, b_off, b_attn,
        wvT, woutT, woaT, bias_oa);
    gemm_dual<<<dim3(850), blk, 0, stream>>>(
        inflat, wvT, b_val, value_bf, query, woaT, bias_oa, offattn);
    msda_sample_v3<<<dim3(2720), blk, 0, stream>>>(
        value_bf, refp, offattn, mid_bf);
    gemm_out<<<dim3(340), blk, 0, stream>>>(
        mid_bf, woutT, b_out, out);
}